// Round 18
// baseline (292.234 us; speedup 1.0000x reference)
//
#include <hip/hip_runtime.h>

// ConeIntersection fused kernel for MI355X (gfx950).
// N=4, B=8192, DIM=1024, HEADS=4, HD=256. Device buffers FP32; comparison in
// bf16 domain (2% of max). Numerics equivalent to passing r3/r8/r10/r15/r17
// kernels (2-term f16 RNE splits, 3 MFMAs/product axis path; plain f16 arg
// path; pre-scaled x16, scores /256).
//
// Round-18 = r17 (best, 288us) + LDS squeeze for 4 blocks/CU:
//  - SEQUENTIAL operand staging: stage axis (hi/lo 32KB) -> axis pass ->
//    re-stage arg into the SAME buffers -> arg pass -> h1 overlays them.
//    LDS 64KB -> 40KB/block => 4 blocks/CU (160KB exactly).
//  - launch_bounds(512,4): empirical VGPR cap 64; r17 used 56 -> fits.
//  - 4-way cross-block phase diversity (stage/mfma/valu phases overlap
//    across blocks; setprio arbitrates in favor of MFMA waves).
//  - Unchanged: 32x32x16 MFMA + T5 setprio, widened swizzle, depth-2 weight
//    dbuf, 8 pairs/block, grid 4096 XCD-swizzled, frag-linear weights.

typedef __attribute__((ext_vector_type(8))) _Float16 f16x8;
typedef __attribute__((ext_vector_type(8))) float f32x8;
typedef __attribute__((ext_vector_type(4))) float f32x4;
typedef __attribute__((ext_vector_type(16))) float f32x16;

#define BH 32768            // B*HEADS pairs
#define OUT_ARG_OFF 8388608 // B*DIM

// ws layout in halfs (fragment-linear within each array)
#define O_WXA_H 0
#define O_WXA_L 65536
#define O_WXR_H 131072
#define O_WXR_L 196608
#define O_WRA_H 262144
#define O_WRR_H 327680
#define O_W2X_H 393216
#define O_W2X_L 458752
#define O_W2G_H 524288
#define WS_HALFS 589824     // 1179648 bytes

__device__ __forceinline__ void split16(float x, _Float16& hi, _Float16& lo) {
  float xs = x * 16.0f;
  _Float16 h = (_Float16)xs;      // RNE
  hi = h;
  lo = (_Float16)(xs - (float)h); // residual; product error ~2^-22
}

// 16x16x32 fragment-linear (gate GEMM): lane ((k>>3)&3)*16+(o&15), slot k&7
__device__ __forceinline__ int fragidx16(int o, int k) {
  return ((o >> 4) * 8 + (k >> 5)) * 512 + ((((k >> 3) & 3) << 4) + (o & 15)) * 8 + (k & 7);
}
// 32x32x16 fragment-linear: tile o>>5, step k>>4; lane ((k>>3)&1)*32+(o&31)
__device__ __forceinline__ int fragidx32(int o, int k) {
  return ((o >> 5) * 16 + (k >> 4)) * 512 + ((((k >> 3) & 1) << 5) + (o & 31)) * 8 + (k & 7);
}

// ---- prep: combined + split layer weights (x16-scaled, frag-linear) ----
__global__ void combine_weights(const float* __restrict__ Wx1, const float* __restrict__ Wr1,
                                const float* __restrict__ W2x, const float* __restrict__ W2g,
                                _Float16* __restrict__ ws) {
  int i = blockIdx.x * 256 + threadIdx.x;  // 0..65535 ; o=i>>8, k=i&255
  int o = i >> 8, k = i & 255;
  int d = fragidx32(o, k);
  float a = Wx1[o * 512 + k], b = Wx1[o * 512 + 256 + k];
  _Float16 h, l;
  split16(a + b, h, l);          ws[O_WXA_H + d] = h; ws[O_WXA_L + d] = l;
  split16(0.5f * (b - a), h, l); ws[O_WXR_H + d] = h; ws[O_WXR_L + d] = l;
  a = Wr1[o * 512 + k]; b = Wr1[o * 512 + 256 + k];
  ws[O_WRA_H + d] = (_Float16)((a + b) * 16.0f);
  ws[O_WRR_H + d] = (_Float16)((0.5f * (b - a)) * 16.0f);
  split16(W2x[o * 256 + k], h, l); ws[O_W2X_H + d] = h; ws[O_W2X_L + d] = l;
  ws[O_W2G_H + fragidx16(o, k)] = (_Float16)(W2g[o * 256 + k] * 16.0f);
}

#define MFMA16 __builtin_amdgcn_mfma_f32_16x16x32_f16
#define MFMA32 __builtin_amdgcn_mfma_f32_32x32x16_f16

// stage one fp32 operand (32 rows x 256 cols) -> reg split16 -> swizzled LDS
__device__ __forceinline__ void stage32(const float* __restrict__ src, int g0, int tid,
                                        _Float16* bufH, _Float16* bufL) {
  #pragma unroll
  for (int c = 0; c < 2; ++c) {
    const int i   = c * 512 + tid;
    const int row = i >> 5;            // 0..31 ; n = row&3, pair = row>>2
    const int col = (i & 31) * 8;
    const int gofs = ((row & 3) * BH + g0 + (row >> 2)) * 256 + col;
    f32x8 v = *(const f32x8*)(src + gofs);
    f16x8 xh, xl;
    #pragma unroll
    for (int j = 0; j < 8; ++j) { _Float16 h, lo2; split16(v[j], h, lo2); xh[j] = h; xl[j] = lo2; }
    const int ad = row * 256 + (col ^ ((row & 31) << 3));
    *(f16x8*)(bufH + ad) = xh;
    *(f16x8*)(bufL + ad) = xl;
  }
}

// one GEMM1 operand pass (32x32x16): operand hi/lo in LDS; dbuf weights.
__device__ __forceinline__ void gemm1_pass32(const _Float16* __restrict__ ws,
                                             int oBh, int oBl, int oBm,
                                             const _Float16* bufH, const _Float16* bufL,
                                             int w, int l,
                                             f32x16& acc1, f32x16& accm) {
  const int row = l & 31;
  const int hi8 = (l >> 5) << 3;
  f16x8 wh[2], wl[2], wm[2];
  {
    const int fb = (w * 16) * 512 + l * 8;
    wh[0] = *(const f16x8*)(ws + oBh + fb);
    wl[0] = *(const f16x8*)(ws + oBl + fb);
    wm[0] = *(const f16x8*)(ws + oBm + fb);
  }
  #pragma unroll
  for (int st = 0; st < 16; ++st) {
    const int cur = st & 1, nx = cur ^ 1;
    if (st < 15) {
      const int fb = (w * 16 + st + 1) * 512 + l * 8;
      wh[nx] = *(const f16x8*)(ws + oBh + fb);
      wl[nx] = *(const f16x8*)(ws + oBl + fb);
      wm[nx] = *(const f16x8*)(ws + oBm + fb);
    }
    const int ad = row * 256 + ((st * 16 + hi8) ^ ((row & 31) << 3));
    const f16x8 ah = *(const f16x8*)(bufH + ad);
    const f16x8 al = *(const f16x8*)(bufL + ad);
    __builtin_amdgcn_s_setprio(1);
    acc1 = MFMA32(ah, wh[cur], acc1, 0, 0, 0);
    acc1 = MFMA32(al, wh[cur], acc1, 0, 0, 0);
    acc1 = MFMA32(ah, wl[cur], acc1, 0, 0, 0);
    accm = MFMA32(ah, wm[cur], accm, 0, 0, 0);
    __builtin_amdgcn_s_setprio(0);
  }
}

__global__ __launch_bounds__(512, 4)
void cone_main(const float* __restrict__ axisF, const float* __restrict__ argF,
               const float* __restrict__ bx1, const float* __restrict__ br1,
               const float* __restrict__ bg2,
               const _Float16* __restrict__ ws, float* __restrict__ out)
{
  __shared__ __align__(16) _Float16 lds[20480];  // 40KB -> 4 blocks/CU
  _Float16* bufH = lds;            // 32x256: axis hi -> arg hi -> h1h
  _Float16* bufL = lds + 8192;     // 32x256: axis lo -> arg lo -> h1l
  _Float16* h1m  = lds + 16384;    // 16x256: mean relu(h1_arg)

  const int tid = threadIdx.x;
  const int w   = tid >> 6;          // wave 0..7; owns cols [w*32, w*32+32)
  const int l   = tid & 63;
  const int l15 = l & 15;
  const int lg  = l >> 4;
  const int l31 = l & 31;
  const int lh  = l >> 5;            // 0/1
  int bid = blockIdx.x;
  bid = ((bid & 7) << 9) + (bid >> 3);   // XCD swizzle (4096 % 8 == 0)
  const int g0 = bid << 3;               // 8 pairs/block
  const float s = 1.0f / 256.0f;

  f32x16 acc1, accm;
  #pragma unroll
  for (int i = 0; i < 16; ++i) { acc1[i] = 0.f; accm[i] = 0.f; }

  // ---- phase A: stage axis, axis-operand pass ----
  stage32(axisF, g0, tid, bufH, bufL);
  __syncthreads();
  gemm1_pass32(ws, O_WXA_H, O_WXA_L, O_WRA_H, bufH, bufL, w, l, acc1, accm);
  __syncthreads();   // done reading axis staging

  // ---- phase B: stage arg into same buffers, arg-operand pass ----
  stage32(argF, g0, tid, bufH, bufL);
  __syncthreads();
  gemm1_pass32(ws, O_WXR_H, O_WXR_L, O_WRR_H, bufH, bufL, w, l, acc1, accm);
  __syncthreads();   // done reading arg staging

  // ---------- epilogue 1: h1 (split) overlays bufH/bufL; h1m mean ----------
  _Float16* h1h = bufH;   // 32x256
  _Float16* h1l = bufL;   // 32x256
  // zero h1m rows 8..15 (gate A-tile is 16 rows; only 8 pairs live)
  *(unsigned long long*)&h1m[2048 + tid * 4] = 0ull;
  {
    const int c = (w << 5) + l31;
    const float bvx = bx1[c];
    const float bvr = br1[c];
    #pragma unroll
    for (int g = 0; g < 4; ++g) {
      float sm = 0.f;
      #pragma unroll
      for (int n = 0; n < 4; ++n) {
        const int r = g * 4 + n;
        const int row = (r & 3) + 8 * (r >> 2) + 4 * lh;  // = pair*4 + n
        const float v = fmaxf(acc1[r] * s + bvx, 0.f);
        _Float16 h, lo2; split16(v, h, lo2);
        const int ad = row * 256 + (c ^ ((row & 31) << 3));
        h1h[ad] = h; h1l[ad] = lo2;
        sm += fmaxf(accm[r] * s + bvr, 0.f);
      }
      const int p = 2 * g + lh;   // pair index 0..7
      h1m[p * 256 + (c ^ ((p & 7) << 3))] = (_Float16)(0.25f * sm * 16.0f);
    }
  }
  __syncthreads();

  // ---------- GEMM2 (attn logits, split, 32x32x16) ----------
  f32x16 acc2;
  #pragma unroll
  for (int i = 0; i < 16; ++i) acc2[i] = 0.f;
  {
    const int row = l31;
    const int hi8 = lh << 3;
    f16x8 w2h[2], w2l[2];
    {
      const int fb = (w * 16) * 512 + l * 8;
      w2h[0] = *(const f16x8*)(ws + O_W2X_H + fb);
      w2l[0] = *(const f16x8*)(ws + O_W2X_L + fb);
    }
    #pragma unroll
    for (int st = 0; st < 16; ++st) {
      const int cur = st & 1, nx = cur ^ 1;
      if (st < 15) {
        const int fb = (w * 16 + st + 1) * 512 + l * 8;
        w2h[nx] = *(const f16x8*)(ws + O_W2X_H + fb);
        w2l[nx] = *(const f16x8*)(ws + O_W2X_L + fb);
      }
      const int ad = row * 256 + ((st * 16 + hi8) ^ ((row & 31) << 3));
      const f16x8 ah = *(const f16x8*)(h1h + ad);
      const f16x8 al = *(const f16x8*)(h1l + ad);
      __builtin_amdgcn_s_setprio(1);
      acc2 = MFMA32(ah, w2h[cur], acc2, 0, 0, 0);
      acc2 = MFMA32(al, w2h[cur], acc2, 0, 0, 0);
      acc2 = MFMA32(ah, w2l[cur], acc2, 0, 0, 0);
      __builtin_amdgcn_s_setprio(0);
    }
  }

  // ---------- gate GEMM (16x16x32, h1m 16 rows) ----------
  f32x4 acc3[2];
  acc3[0] = (f32x4){0, 0, 0, 0}; acc3[1] = (f32x4){0, 0, 0, 0};
  {
    f16x8 wg[2][2];
    #pragma unroll
    for (int nt = 0; nt < 2; ++nt)
      wg[0][nt] = *(const f16x8*)(ws + O_W2G_H + (((w << 1) + nt) << 3) * 512 + l * 8);
    #pragma unroll
    for (int kk = 0; kk < 8; ++kk) {
      const int cur = kk & 1, nx = cur ^ 1;
      if (kk < 7) {
        #pragma unroll
        for (int nt = 0; nt < 2; ++nt)
          wg[nx][nt] = *(const f16x8*)(ws + O_W2G_H + ((((w << 1) + nt) << 3) + kk + 1) * 512 + l * 8);
      }
      const int k0 = (kk << 5) + (lg << 3);
      const f16x8 am = *(const f16x8*)&h1m[l15 * 256 + (k0 ^ ((l15 & 7) << 3))];
      acc3[0] = MFMA16(am, wg[cur][0], acc3[0], 0, 0, 0);
      acc3[1] = MFMA16(am, wg[cur][1], acc3[1], 0, 0, 0);
    }
  }

  // ---- softmax over n (in-lane reg quads) + circular mean -> axis_out ----
  // b_axis2 omitted: constant per column across n, cancels in softmax(axis=0).
  {
    const int c = (w << 5) + l31;
    float av[4][4];
    #pragma unroll
    for (int g = 0; g < 4; ++g) {
      const int gi = g0 + 2 * g + lh;
      #pragma unroll
      for (int n = 0; n < 4; ++n) av[g][n] = axisF[(n * BH + gi) * 256 + c];
    }
    #pragma unroll
    for (int g = 0; g < 4; ++g) {
      float lv[4];
      #pragma unroll
      for (int n = 0; n < 4; ++n) lv[n] = acc2[g * 4 + n] * s;
      const float mx = fmaxf(fmaxf(lv[0], lv[1]), fmaxf(lv[2], lv[3]));
      float e[4]; float sum = 0.f;
      #pragma unroll
      for (int n = 0; n < 4; ++n) { e[n] = __expf(lv[n] - mx); sum += e[n]; }
      const float inv = 1.f / sum;
      float x = 0.f, y = 0.f;
      #pragma unroll
      for (int n = 0; n < 4; ++n) {
        float sn, cs2;
        __sincosf(av[g][n], &sn, &cs2);
        const float at = e[n] * inv;
        x += at * cs2;
        y += at * sn;
      }
      if (fabsf(x) < 0.001f) x = 0.001f;
      const int gi = g0 + 2 * g + lh;
      out[gi * 256 + c] = atan2f(y, x);   // == arctan+quadrant correction
    }
  }

  // ---- sigmoid gate * min_n arg -> arg_out (fp32) ----
  {
    #pragma unroll
    for (int nt = 0; nt < 2; ++nt) {
      const int c = (w << 5) + (nt << 4) + l15;
      const float bgv = bg2[c];
      float ag[4][4];
      #pragma unroll
      for (int r = 0; r < 4; ++r) {
        const int p = (lg << 2) + r;
        if (p < 8) {
          const int gi = g0 + p;
          #pragma unroll
          for (int n = 0; n < 4; ++n) ag[r][n] = argF[(n * BH + gi) * 256 + c];
        }
      }
      #pragma unroll
      for (int r = 0; r < 4; ++r) {
        const int p = (lg << 2) + r;   // gate C row = pair index; only 0..7 live
        if (p < 8) {
          const int gi = g0 + p;
          const float gate = 1.f / (1.f + __expf(-(acc3[nt][r] * s + bgv)));
          const float mn = fminf(fminf(ag[r][0], ag[r][1]), fminf(ag[r][2], ag[r][3]));
          out[OUT_ARG_OFF + gi * 256 + c] = mn * gate;
        }
      }
    }
  }
}

extern "C" void kernel_launch(void* const* d_in, const int* in_sizes, int n_in,
                              void* d_out, int out_size, void* d_ws, size_t ws_size,
                              hipStream_t stream) {
  const float* axisF = (const float*)d_in[0];
  const float* argF  = (const float*)d_in[1];
  const float* Wx1   = (const float*)d_in[2];
  const float* bx1   = (const float*)d_in[3];
  const float* Wr1   = (const float*)d_in[4];
  const float* br1   = (const float*)d_in[5];
  const float* W2x   = (const float*)d_in[6];
  // d_in[7] = b_axis2: constant over n at fixed column -> cancels in softmax
  const float* W2g   = (const float*)d_in[8];
  const float* bg2   = (const float*)d_in[9];
  float* out = (float*)d_out;
  _Float16* ws = (_Float16*)d_ws;

  combine_weights<<<256, 256, 0, stream>>>(Wx1, Wr1, W2x, W2g, ws);
  cone_main<<<4096, 512, 0, stream>>>(axisF, argF, bx1, br1, bg2, ws, out);
}

// Round 19
// 286.544 us; speedup vs baseline: 1.0199x; 1.0199x over previous
//
#include <hip/hip_runtime.h>

// ConeIntersection fused kernel for MI355X (gfx950).
// N=4, B=8192, DIM=1024, HEADS=4, HD=256. Device buffers FP32; comparison in
// bf16 domain (2% of max). Numerics equivalent to passing r3/r8/r10/r15/r17
// kernels (2-term f16 RNE splits, 3 MFMAs/product axis path; plain f16 arg
// path; pre-scaled x16, scores /256).
//
// Round-19 = r17 (best, 288us; r18's 40KB/sequential-staging reverted) + ONE
// isolated change: weight prefetch depth 2 -> 3 (2 load-sets in flight,
// ~2x L2-latency cover) in GEMM1 passes and GEMM2. r16's depth-4 regression
// was confounded with the av-hoist; this isolates depth alone.

typedef __attribute__((ext_vector_type(8))) _Float16 f16x8;
typedef __attribute__((ext_vector_type(8))) float f32x8;
typedef __attribute__((ext_vector_type(4))) float f32x4;
typedef __attribute__((ext_vector_type(16))) float f32x16;

#define BH 32768            // B*HEADS pairs
#define OUT_ARG_OFF 8388608 // B*DIM

// ws layout in halfs (fragment-linear within each array)
#define O_WXA_H 0
#define O_WXA_L 65536
#define O_WXR_H 131072
#define O_WXR_L 196608
#define O_WRA_H 262144
#define O_WRR_H 327680
#define O_W2X_H 393216
#define O_W2X_L 458752
#define O_W2G_H 524288
#define WS_HALFS 589824     // 1179648 bytes

__device__ __forceinline__ void split16(float x, _Float16& hi, _Float16& lo) {
  float xs = x * 16.0f;
  _Float16 h = (_Float16)xs;      // RNE
  hi = h;
  lo = (_Float16)(xs - (float)h); // residual; product error ~2^-22
}

// 16x16x32 fragment-linear (gate GEMM): lane ((k>>3)&3)*16+(o&15), slot k&7
__device__ __forceinline__ int fragidx16(int o, int k) {
  return ((o >> 4) * 8 + (k >> 5)) * 512 + ((((k >> 3) & 3) << 4) + (o & 15)) * 8 + (k & 7);
}
// 32x32x16 fragment-linear: tile o>>5, step k>>4; lane ((k>>3)&1)*32+(o&31)
__device__ __forceinline__ int fragidx32(int o, int k) {
  return ((o >> 5) * 16 + (k >> 4)) * 512 + ((((k >> 3) & 1) << 5) + (o & 31)) * 8 + (k & 7);
}

// ---- prep: combined + split layer weights (x16-scaled, frag-linear) ----
__global__ void combine_weights(const float* __restrict__ Wx1, const float* __restrict__ Wr1,
                                const float* __restrict__ W2x, const float* __restrict__ W2g,
                                _Float16* __restrict__ ws) {
  int i = blockIdx.x * 256 + threadIdx.x;  // 0..65535 ; o=i>>8, k=i&255
  int o = i >> 8, k = i & 255;
  int d = fragidx32(o, k);
  float a = Wx1[o * 512 + k], b = Wx1[o * 512 + 256 + k];
  _Float16 h, l;
  split16(a + b, h, l);          ws[O_WXA_H + d] = h; ws[O_WXA_L + d] = l;
  split16(0.5f * (b - a), h, l); ws[O_WXR_H + d] = h; ws[O_WXR_L + d] = l;
  a = Wr1[o * 512 + k]; b = Wr1[o * 512 + 256 + k];
  ws[O_WRA_H + d] = (_Float16)((a + b) * 16.0f);
  ws[O_WRR_H + d] = (_Float16)((0.5f * (b - a)) * 16.0f);
  split16(W2x[o * 256 + k], h, l); ws[O_W2X_H + d] = h; ws[O_W2X_L + d] = l;
  ws[O_W2G_H + fragidx16(o, k)] = (_Float16)(W2g[o * 256 + k] * 16.0f);
}

#define MFMA16 __builtin_amdgcn_mfma_f32_16x16x32_f16
#define MFMA32 __builtin_amdgcn_mfma_f32_32x32x16_f16

// one GEMM1 operand pass (32x32x16): operand hi/lo in LDS; depth-3 weights.
__device__ __forceinline__ void gemm1_pass32(const _Float16* __restrict__ ws,
                                             int oBh, int oBl, int oBm,
                                             const _Float16* bufH, const _Float16* bufL,
                                             int w, int l,
                                             f32x16& acc1, f32x16& accm) {
  const int row = l & 31;
  const int hi8 = (l >> 5) << 3;
  f16x8 wh[3], wl[3], wm[3];
  #pragma unroll
  for (int p = 0; p < 2; ++p) {
    const int fb = (w * 16 + p) * 512 + l * 8;
    wh[p] = *(const f16x8*)(ws + oBh + fb);
    wl[p] = *(const f16x8*)(ws + oBl + fb);
    wm[p] = *(const f16x8*)(ws + oBm + fb);
  }
  #pragma unroll
  for (int st = 0; st < 16; ++st) {
    const int cur = st % 3;
    if (st < 14) {
      const int nx = (st + 2) % 3;
      const int fb = (w * 16 + st + 2) * 512 + l * 8;
      wh[nx] = *(const f16x8*)(ws + oBh + fb);
      wl[nx] = *(const f16x8*)(ws + oBl + fb);
      wm[nx] = *(const f16x8*)(ws + oBm + fb);
    }
    const int ad = row * 256 + ((st * 16 + hi8) ^ ((row & 31) << 3));
    const f16x8 ah = *(const f16x8*)(bufH + ad);
    const f16x8 al = *(const f16x8*)(bufL + ad);
    __builtin_amdgcn_s_setprio(1);
    acc1 = MFMA32(ah, wh[cur], acc1, 0, 0, 0);
    acc1 = MFMA32(al, wh[cur], acc1, 0, 0, 0);
    acc1 = MFMA32(ah, wl[cur], acc1, 0, 0, 0);
    accm = MFMA32(ah, wm[cur], accm, 0, 0, 0);
    __builtin_amdgcn_s_setprio(0);
  }
}

__global__ __launch_bounds__(512, 2)
void cone_main(const float* __restrict__ axisF, const float* __restrict__ argF,
               const float* __restrict__ bx1, const float* __restrict__ br1,
               const float* __restrict__ bg2,
               const _Float16* __restrict__ ws, float* __restrict__ out)
{
  __shared__ __align__(16) _Float16 lds[32768];  // 64KB
  _Float16* bufAxH = lds;            // 32x256 axis hi  -> later h1h
  _Float16* bufAxL = lds + 8192;     // 32x256 axis lo  -> later h1l
  _Float16* bufArH = lds + 16384;    // 32x256 arg hi   -> later h1m (16x256)
  _Float16* bufArL = lds + 24576;    // 32x256 arg lo

  const int tid = threadIdx.x;
  const int w   = tid >> 6;          // wave 0..7; owns cols [w*32, w*32+32)
  const int l   = tid & 63;
  const int l15 = l & 15;
  const int lg  = l >> 4;
  const int l31 = l & 31;
  const int lh  = l >> 5;            // 0/1
  int bid = blockIdx.x;
  bid = ((bid & 7) << 9) + (bid >> 3);   // XCD swizzle (4096 % 8 == 0)
  const int g0 = bid << 3;               // 8 pairs/block
  const float s = 1.0f / 256.0f;

  // ---------- stage A tiles: fp32 global -> reg split16 -> swizzled LDS ----
  {
    #pragma unroll
    for (int c = 0; c < 2; ++c) {
      const int i   = c * 512 + tid;
      const int row = i >> 5;            // 0..31 ; n = row&3, pair = row>>2
      const int col = (i & 31) * 8;
      const int gofs = ((row & 3) * BH + g0 + (row >> 2)) * 256 + col;
      f32x8 va = *(const f32x8*)(axisF + gofs);
      f32x8 vr = *(const f32x8*)(argF + gofs);
      f16x8 xh, xl, rh, rl;
      #pragma unroll
      for (int j = 0; j < 8; ++j) {
        _Float16 h, lo2;
        split16(va[j], h, lo2); xh[j] = h; xl[j] = lo2;
        split16(vr[j], h, lo2); rh[j] = h; rl[j] = lo2;
      }
      const int ad = row * 256 + (col ^ ((row & 31) << 3));
      *(f16x8*)(bufAxH + ad) = xh;
      *(f16x8*)(bufAxL + ad) = xl;
      *(f16x8*)(bufArH + ad) = rh;
      *(f16x8*)(bufArL + ad) = rl;
    }
  }
  __syncthreads();

  // ---------- GEMM1: two operand passes, 32x32x16 ----------
  f32x16 acc1, accm;
  #pragma unroll
  for (int i = 0; i < 16; ++i) { acc1[i] = 0.f; accm[i] = 0.f; }

  gemm1_pass32(ws, O_WXA_H, O_WXA_L, O_WRA_H, bufAxH, bufAxL, w, l, acc1, accm);
  gemm1_pass32(ws, O_WXR_H, O_WXR_L, O_WRR_H, bufArH, bufArL, w, l, acc1, accm);
  __syncthreads();   // all waves done reading bufAx/bufAr

  // ---------- epilogue 1: h1 (split) -> LDS overlay; h1m mean -> LDS ----
  _Float16* h1h = bufAxH;   // 32x256
  _Float16* h1l = bufAxL;   // 32x256
  _Float16* h1m = bufArH;   // 16x256 (rows 8..15 zeroed)
  *(unsigned long long*)&h1m[2048 + tid * 4] = 0ull;
  {
    const int c = (w << 5) + l31;
    const float bvx = bx1[c];
    const float bvr = br1[c];
    #pragma unroll
    for (int g = 0; g < 4; ++g) {
      float sm = 0.f;
      #pragma unroll
      for (int n = 0; n < 4; ++n) {
        const int r = g * 4 + n;
        const int row = (r & 3) + 8 * (r >> 2) + 4 * lh;  // = pair*4 + n
        const float v = fmaxf(acc1[r] * s + bvx, 0.f);
        _Float16 h, lo2; split16(v, h, lo2);
        const int ad = row * 256 + (c ^ ((row & 31) << 3));
        h1h[ad] = h; h1l[ad] = lo2;
        sm += fmaxf(accm[r] * s + bvr, 0.f);
      }
      const int p = 2 * g + lh;   // pair index 0..7
      h1m[p * 256 + (c ^ ((p & 7) << 3))] = (_Float16)(0.25f * sm * 16.0f);
    }
  }
  __syncthreads();

  // ---------- GEMM2 (attn logits, split, 32x32x16, depth-3 weights) ----------
  f32x16 acc2;
  #pragma unroll
  for (int i = 0; i < 16; ++i) acc2[i] = 0.f;
  {
    const int row = l31;
    const int hi8 = lh << 3;
    f16x8 w2h[3], w2l[3];
    #pragma unroll
    for (int p = 0; p < 2; ++p) {
      const int fb = (w * 16 + p) * 512 + l * 8;
      w2h[p] = *(const f16x8*)(ws + O_W2X_H + fb);
      w2l[p] = *(const f16x8*)(ws + O_W2X_L + fb);
    }
    #pragma unroll
    for (int st = 0; st < 16; ++st) {
      const int cur = st % 3;
      if (st < 14) {
        const int nx = (st + 2) % 3;
        const int fb = (w * 16 + st + 2) * 512 + l * 8;
        w2h[nx] = *(const f16x8*)(ws + O_W2X_H + fb);
        w2l[nx] = *(const f16x8*)(ws + O_W2X_L + fb);
      }
      const int ad = row * 256 + ((st * 16 + hi8) ^ ((row & 31) << 3));
      const f16x8 ah = *(const f16x8*)(h1h + ad);
      const f16x8 al = *(const f16x8*)(h1l + ad);
      __builtin_amdgcn_s_setprio(1);
      acc2 = MFMA32(ah, w2h[cur], acc2, 0, 0, 0);
      acc2 = MFMA32(al, w2h[cur], acc2, 0, 0, 0);
      acc2 = MFMA32(ah, w2l[cur], acc2, 0, 0, 0);
      __builtin_amdgcn_s_setprio(0);
    }
  }

  // ---------- gate GEMM (16x16x32, h1m 16 rows) ----------
  f32x4 acc3[2];
  acc3[0] = (f32x4){0, 0, 0, 0}; acc3[1] = (f32x4){0, 0, 0, 0};
  {
    f16x8 wg[2][2];
    #pragma unroll
    for (int nt = 0; nt < 2; ++nt)
      wg[0][nt] = *(const f16x8*)(ws + O_W2G_H + (((w << 1) + nt) << 3) * 512 + l * 8);
    #pragma unroll
    for (int kk = 0; kk < 8; ++kk) {
      const int cur = kk & 1, nx = cur ^ 1;
      if (kk < 7) {
        #pragma unroll
        for (int nt = 0; nt < 2; ++nt)
          wg[nx][nt] = *(const f16x8*)(ws + O_W2G_H + ((((w << 1) + nt) << 3) + kk + 1) * 512 + l * 8);
      }
      const int k0 = (kk << 5) + (lg << 3);
      const f16x8 am = *(const f16x8*)&h1m[l15 * 256 + (k0 ^ ((l15 & 7) << 3))];
      acc3[0] = MFMA16(am, wg[cur][0], acc3[0], 0, 0, 0);
      acc3[1] = MFMA16(am, wg[cur][1], acc3[1], 0, 0, 0);
    }
  }

  // ---- softmax over n (in-lane reg quads) + circular mean -> axis_out ----
  // b_axis2 omitted: constant per column across n, cancels in softmax(axis=0).
  {
    const int c = (w << 5) + l31;
    float av[4][4];
    #pragma unroll
    for (int g = 0; g < 4; ++g) {
      const int gi = g0 + 2 * g + lh;
      #pragma unroll
      for (int n = 0; n < 4; ++n) av[g][n] = axisF[(n * BH + gi) * 256 + c];
    }
    #pragma unroll
    for (int g = 0; g < 4; ++g) {
      float lv[4];
      #pragma unroll
      for (int n = 0; n < 4; ++n) lv[n] = acc2[g * 4 + n] * s;
      const float mx = fmaxf(fmaxf(lv[0], lv[1]), fmaxf(lv[2], lv[3]));
      float e[4]; float sum = 0.f;
      #pragma unroll
      for (int n = 0; n < 4; ++n) { e[n] = __expf(lv[n] - mx); sum += e[n]; }
      const float inv = 1.f / sum;
      float x = 0.f, y = 0.f;
      #pragma unroll
      for (int n = 0; n < 4; ++n) {
        float sn, cs2;
        __sincosf(av[g][n], &sn, &cs2);
        const float at = e[n] * inv;
        x += at * cs2;
        y += at * sn;
      }
      if (fabsf(x) < 0.001f) x = 0.001f;
      const int gi = g0 + 2 * g + lh;
      out[gi * 256 + c] = atan2f(y, x);   // == arctan+quadrant correction
    }
  }

  // ---- sigmoid gate * min_n arg -> arg_out (fp32) ----
  {
    #pragma unroll
    for (int nt = 0; nt < 2; ++nt) {
      const int c = (w << 5) + (nt << 4) + l15;
      const float bgv = bg2[c];
      float ag[4][4];
      #pragma unroll
      for (int r = 0; r < 4; ++r) {
        const int p = (lg << 2) + r;
        if (p < 8) {
          const int gi = g0 + p;
          #pragma unroll
          for (int n = 0; n < 4; ++n) ag[r][n] = argF[(n * BH + gi) * 256 + c];
        }
      }
      #pragma unroll
      for (int r = 0; r < 4; ++r) {
        const int p = (lg << 2) + r;   // gate C row = pair index; only 0..7 live
        if (p < 8) {
          const int gi = g0 + p;
          const float gate = 1.f / (1.f + __expf(-(acc3[nt][r] * s + bgv)));
          const float mn = fminf(fminf(ag[r][0], ag[r][1]), fminf(ag[r][2], ag[r][3]));
          out[OUT_ARG_OFF + gi * 256 + c] = mn * gate;
        }
      }
    }
  }
}

extern "C" void kernel_launch(void* const* d_in, const int* in_sizes, int n_in,
                              void* d_out, int out_size, void* d_ws, size_t ws_size,
                              hipStream_t stream) {
  const float* axisF = (const float*)d_in[0];
  const float* argF  = (const float*)d_in[1];
  const float* Wx1   = (const float*)d_in[2];
  const float* bx1   = (const float*)d_in[3];
  const float* Wr1   = (const float*)d_in[4];
  const float* br1   = (const float*)d_in[5];
  const float* W2x   = (const float*)d_in[6];
  // d_in[7] = b_axis2: constant over n at fixed column -> cancels in softmax
  const float* W2g   = (const float*)d_in[8];
  const float* bg2   = (const float*)d_in[9];
  float* out = (float*)d_out;
  _Float16* ws = (_Float16*)d_ws;

  combine_weights<<<256, 256, 0, stream>>>(Wx1, Wr1, W2x, W2g, ws);
  cone_main<<<4096, 512, 0, stream>>>(axisF, argF, bx1, br1, bg2, ws, out);
}